// Round 2
// baseline (1525.427 us; speedup 1.0000x reference)
//
#include <hip/hip_runtime.h>

#define BB 8
#define CC_ALL 128
#define HH 160
#define WW 160
#define PAD 4
#define RANGE 9
#define ND 80
#define NG 3                  // di groups (rows 0-2, 3-5, 6-8)
#define DR 3                  // di rows per group
#define TH 8                  // tile height (full width tile: 160 x 8)
#define NTX 40                // lanes per image row
#define PXT 4                 // px per thread along w (aligned float4)
#define NTHREADS 320          // 40 x 8 = 5 waves
#define CCHUNK 4              // smaller chunk: prefetch buffer = 5 float4 (20 VGPR)
#define NROWS (TH + DR - 1)   // 10 f2 rows cover this group's 3 di offsets
#define ROWF (WW + 2 * PAD)   // 168 floats per LDS row (4 pad each side)
#define PLANE (HH * WW)       // 25600
#define NSLOT (CCHUNK * NROWS * (WW / 4) / NTHREADS)  // 5 float4 slots/thread
#define NACC (DR * RANGE * PXT)  // 108

__global__ __launch_bounds__(NTHREADS, 3)
void cost_volume_kernel(const float* __restrict__ f1,
                        const float* __restrict__ f2,
                        float* __restrict__ out) {
    __shared__ __align__(16) float s2[CCHUNK][NROWS][ROWF];   // 26.9 KB

    const int tile_y = blockIdx.x;              // 0..19
    const int bz     = blockIdx.y;              // 0..23
    const int b = bz / NG;
    const int g = bz - b * NG;                  // di group
    const int h0 = tile_y * TH;
    const int tid = threadIdx.x;
    const int tx = tid % NTX;                   // 0..39
    const int ty = tid / NTX;                   // 0..7
    const int w = tx * PXT;                     // multiple of 4
    const int h = h0 + ty;
    const int row_start = h0 + DR * g - PAD;    // image row of LDS row 0

    // ---- zero LDS once: pad columns + OOB rows stay zero forever ----
    {
        float* p = &s2[0][0][0];
        for (int i = tid; i < CCHUNK * NROWS * ROWF; i += NTHREADS) p[i] = 0.f;
    }

    // ---- precompute staging slots (channel-invariant) ----
    // slot s -> (cc, row, quad): covers f2[c0+cc][row_start+row][quad*4 .. +3]
    int glb_off[NSLOT];
    int lds_off[NSLOT];
    unsigned vmask = 0;
    {
#pragma unroll
        for (int k = 0; k < NSLOT; k++) {
            const int s = tid + k * NTHREADS;
            const int quad = s % (WW / 4);
            const int t = s / (WW / 4);
            const int row = t % NROWS;
            const int cc = t / NROWS;
            const int gh = row_start + row;
            glb_off[k] = cc * PLANE + gh * WW + quad * 4;
            lds_off[k] = (cc * NROWS + row) * ROWF + PAD + quad * 4;
            if ((unsigned)gh < HH) vmask |= (1u << k);
        }
    }

    float acc[NACC];
#pragma unroll
    for (int i = 0; i < NACC; i++) acc[i] = 0.f;

    const float* f1p = f1 + (size_t)b * CC_ALL * PLANE + (size_t)h * WW + w;
    const float* f2b = f2 + (size_t)b * CC_ALL * PLANE;
    float* s2f = &s2[0][0][0];

    // ---- prologue: stage chunk 0 ----
    float4 buf[NSLOT];
#pragma unroll
    for (int k = 0; k < NSLOT; k++) {
        if (vmask & (1u << k)) {
            buf[k] = *(const float4*)(f2b + glb_off[k]);   // c0 = 0
        }
    }
    __syncthreads();   // zero-init visible before first staging writes
#pragma unroll
    for (int k = 0; k < NSLOT; k++) {
        if (vmask & (1u << k)) {
            *(float4*)(s2f + lds_off[k]) = buf[k];
        }
    }
    __syncthreads();

    for (int c0 = 0; c0 < CC_ALL; c0 += CCHUNK) {
        const int cn = c0 + CCHUNK;
        // ---- T14 issue-early: prefetch NEXT chunk into registers ----
        if (cn < CC_ALL) {
#pragma unroll
            for (int k = 0; k < NSLOT; k++) {
                if (vmask & (1u << k)) {
                    buf[k] = *(const float4*)(f2b + (size_t)cn * PLANE + glb_off[k]);
                }
            }
        }

        // ---- compute current chunk from LDS (hides prefetch latency) ----
#pragma unroll
        for (int cc = 0; cc < CCHUNK; cc++) {
            const float4 a = *(const float4*)(f1p + (size_t)(c0 + cc) * PLANE);
            const float av[PXT] = {a.x, a.y, a.z, a.w};
#pragma unroll
            for (int r = 0; r < DR; r++) {
                // LDS cols 4tx .. 4tx+11  <->  image w-4 .. w+7 : 3 aligned b128
                const float* rp = &s2[cc][ty + r][w];
                float win[12];
                *(float4*)&win[0] = *(const float4*)(rp);
                *(float4*)&win[4] = *(const float4*)(rp + 4);
                *(float4*)&win[8] = *(const float4*)(rp + 8);
#pragma unroll
                for (int dj = 0; dj < RANGE; dj++) {
#pragma unroll
                    for (int p = 0; p < PXT; p++) {
                        acc[(r * RANGE + dj) * PXT + p] += av[p] * win[dj + p];
                    }
                }
            }
        }
        __syncthreads();   // all waves done reading LDS

        // ---- write-late: commit prefetched registers to LDS ----
        if (cn < CC_ALL) {
#pragma unroll
            for (int k = 0; k < NSLOT; k++) {
                if (vmask & (1u << k)) {
                    *(float4*)(s2f + lds_off[k]) = buf[k];
                }
            }
        }
        __syncthreads();   // staged tile visible
    }

    // ---- epilogue: mean and store (skip center lin==40) ----
    float* ob = out + (size_t)b * ND * PLANE + (size_t)h * WW + w;
#pragma unroll
    for (int r = 0; r < DR; r++) {
#pragma unroll
        for (int dj = 0; dj < RANGE; dj++) {
            const int lin = (DR * g + r) * RANGE + dj;
            if (lin == 40) continue;            // block-uniform branch
            const int d = lin - (lin > 40 ? 1 : 0);
            float4 o;
            o.x = acc[(r * RANGE + dj) * PXT + 0] * (1.f / 128.f);
            o.y = acc[(r * RANGE + dj) * PXT + 1] * (1.f / 128.f);
            o.z = acc[(r * RANGE + dj) * PXT + 2] * (1.f / 128.f);
            o.w = acc[(r * RANGE + dj) * PXT + 3] * (1.f / 128.f);
            *(float4*)(ob + (size_t)d * PLANE) = o;
        }
    }
}

extern "C" void kernel_launch(void* const* d_in, const int* in_sizes, int n_in,
                              void* d_out, int out_size, void* d_ws, size_t ws_size,
                              hipStream_t stream) {
    const float* feat1 = (const float*)d_in[0];
    const float* feat2 = (const float*)d_in[1];
    float* out = (float*)d_out;

    dim3 grid(HH / TH, BB * NG);   // 20 x 24 = 480 blocks
    dim3 block(NTHREADS);
    cost_volume_kernel<<<grid, block, 0, stream>>>(feat1, feat2, out);
}

// Round 3
// 701.699 us; speedup vs baseline: 2.1739x; 2.1739x over previous
//
#include <hip/hip_runtime.h>

#define BB 8
#define CC_ALL 128
#define HH 160
#define WW 160
#define PAD 4
#define RANGE 9
#define ND 80
#define NG 3                  // di groups (rows 0-2, 3-5, 6-8)
#define DR 3                  // di rows per group
#define TH 8                  // tile height (full width tile: 160 x 8)
#define NTX 40                // lanes per image row
#define PXT 4                 // px per thread along w (aligned float4)
#define NTHREADS 320          // 40 x 8 = 5 waves
#define CCHUNK 4              // prefetch buffer = 5 float4 (20 VGPR)
#define NROWS (TH + DR - 1)   // 10 f2 rows cover this group's 3 di offsets
#define ROWF (WW + 2 * PAD)   // 168 floats per LDS row (4 pad each side)
#define PLANE (HH * WW)       // 25600
#define NSLOT (CCHUNK * NROWS * (WW / 4) / NTHREADS)  // 5 float4 slots/thread
#define NACC (DR * RANGE * PXT)  // 108

// NOTE: second launch_bounds arg MUST stay 1. With acc[108] live, any
// min-waves hint makes LLVM cap VGPRs and spill acc to scratch
// (round 2: VGPR=84, 2.1 GB scratch writes, 1381 us).
__global__ __launch_bounds__(NTHREADS, 1)
void cost_volume_kernel(const float* __restrict__ f1,
                        const float* __restrict__ f2,
                        float* __restrict__ out) {
    __shared__ __align__(16) float s2[CCHUNK][NROWS][ROWF];   // 26.9 KB

    const int tile_y = blockIdx.x;              // 0..19
    const int bz     = blockIdx.y;              // 0..23
    const int b = bz / NG;
    const int g = bz - b * NG;                  // di group
    const int h0 = tile_y * TH;
    const int tid = threadIdx.x;
    const int tx = tid % NTX;                   // 0..39
    const int ty = tid / NTX;                   // 0..7
    const int w = tx * PXT;                     // multiple of 4
    const int h = h0 + ty;
    const int row_start = h0 + DR * g - PAD;    // image row of LDS row 0

    // ---- zero LDS once: pad columns + OOB rows stay zero forever ----
    {
        float* p = &s2[0][0][0];
        for (int i = tid; i < CCHUNK * NROWS * ROWF; i += NTHREADS) p[i] = 0.f;
    }

    // ---- precompute staging slots (channel-invariant) ----
    // slot s -> (cc, row, quad): covers f2[c0+cc][row_start+row][quad*4 .. +3]
    int glb_off[NSLOT];
    int lds_off[NSLOT];
    unsigned vmask = 0;
    {
#pragma unroll
        for (int k = 0; k < NSLOT; k++) {
            const int s = tid + k * NTHREADS;
            const int quad = s % (WW / 4);
            const int t = s / (WW / 4);
            const int row = t % NROWS;
            const int cc = t / NROWS;
            const int gh = row_start + row;
            glb_off[k] = cc * PLANE + gh * WW + quad * 4;
            lds_off[k] = (cc * NROWS + row) * ROWF + PAD + quad * 4;
            if ((unsigned)gh < HH) vmask |= (1u << k);
        }
    }

    float acc[NACC];
#pragma unroll
    for (int i = 0; i < NACC; i++) acc[i] = 0.f;

    const float* f1p = f1 + (size_t)b * CC_ALL * PLANE + (size_t)h * WW + w;
    const float* f2b = f2 + (size_t)b * CC_ALL * PLANE;
    float* s2f = &s2[0][0][0];

    // ---- prologue: stage chunk 0 ----
    float4 buf[NSLOT];
#pragma unroll
    for (int k = 0; k < NSLOT; k++) {
        if (vmask & (1u << k)) {
            buf[k] = *(const float4*)(f2b + glb_off[k]);   // c0 = 0
        }
    }
    __syncthreads();   // zero-init visible before first staging writes
#pragma unroll
    for (int k = 0; k < NSLOT; k++) {
        if (vmask & (1u << k)) {
            *(float4*)(s2f + lds_off[k]) = buf[k];
        }
    }
    __syncthreads();

    for (int c0 = 0; c0 < CC_ALL; c0 += CCHUNK) {
        const int cn = c0 + CCHUNK;
        // ---- T14 issue-early: prefetch NEXT chunk into registers ----
        if (cn < CC_ALL) {
#pragma unroll
            for (int k = 0; k < NSLOT; k++) {
                if (vmask & (1u << k)) {
                    buf[k] = *(const float4*)(f2b + (size_t)cn * PLANE + glb_off[k]);
                }
            }
        }

        // ---- compute current chunk from LDS (hides prefetch latency) ----
#pragma unroll
        for (int cc = 0; cc < CCHUNK; cc++) {
            const float4 a = *(const float4*)(f1p + (size_t)(c0 + cc) * PLANE);
            const float av[PXT] = {a.x, a.y, a.z, a.w};
#pragma unroll
            for (int r = 0; r < DR; r++) {
                // LDS cols 4tx .. 4tx+11  <->  image w-4 .. w+7 : 3 aligned b128
                const float* rp = &s2[cc][ty + r][w];
                float win[12];
                *(float4*)&win[0] = *(const float4*)(rp);
                *(float4*)&win[4] = *(const float4*)(rp + 4);
                *(float4*)&win[8] = *(const float4*)(rp + 8);
#pragma unroll
                for (int dj = 0; dj < RANGE; dj++) {
#pragma unroll
                    for (int p = 0; p < PXT; p++) {
                        acc[(r * RANGE + dj) * PXT + p] += av[p] * win[dj + p];
                    }
                }
            }
        }
        __syncthreads();   // all waves done reading LDS

        // ---- write-late: commit prefetched registers to LDS ----
        if (cn < CC_ALL) {
#pragma unroll
            for (int k = 0; k < NSLOT; k++) {
                if (vmask & (1u << k)) {
                    *(float4*)(s2f + lds_off[k]) = buf[k];
                }
            }
        }
        __syncthreads();   // staged tile visible
    }

    // ---- epilogue: mean and store (skip center lin==40) ----
    float* ob = out + (size_t)b * ND * PLANE + (size_t)h * WW + w;
#pragma unroll
    for (int r = 0; r < DR; r++) {
#pragma unroll
        for (int dj = 0; dj < RANGE; dj++) {
            const int lin = (DR * g + r) * RANGE + dj;
            if (lin == 40) continue;            // block-uniform branch
            const int d = lin - (lin > 40 ? 1 : 0);
            float4 o;
            o.x = acc[(r * RANGE + dj) * PXT + 0] * (1.f / 128.f);
            o.y = acc[(r * RANGE + dj) * PXT + 1] * (1.f / 128.f);
            o.z = acc[(r * RANGE + dj) * PXT + 2] * (1.f / 128.f);
            o.w = acc[(r * RANGE + dj) * PXT + 3] * (1.f / 128.f);
            *(float4*)(ob + (size_t)d * PLANE) = o;
        }
    }
}

extern "C" void kernel_launch(void* const* d_in, const int* in_sizes, int n_in,
                              void* d_out, int out_size, void* d_ws, size_t ws_size,
                              hipStream_t stream) {
    const float* feat1 = (const float*)d_in[0];
    const float* feat2 = (const float*)d_in[1];
    float* out = (float*)d_out;

    dim3 grid(HH / TH, BB * NG);   // 20 x 24 = 480 blocks
    dim3 block(NTHREADS);
    cost_volume_kernel<<<grid, block, 0, stream>>>(feat1, feat2, out);
}

// Round 4
// 346.192 us; speedup vs baseline: 4.4063x; 2.0269x over previous
//
#include <hip/hip_runtime.h>

#define BB 8
#define CC_ALL 128
#define HH 160
#define WW 160
#define PAD 4
#define RANGE 9
#define ND 80
#define NG 3                  // di groups (rows 0-2, 3-5, 6-8)
#define DR 3                  // di rows per group -> one per thread now
#define TH 8                  // tile height (full width tile: 160 x 8)
#define NTX 40                // lanes per image row
#define PXT 4                 // px per thread along w (aligned float4)
#define NTHREADS 960          // tx(40) * r(3) * ty(8) = 15 waves
#define CCHUNK 8
#define NROWS (TH + DR - 1)   // 10 f2 rows cover this group's 3 di offsets
#define ROWF (WW + 2 * PAD)   // 168 floats per LDS row (4 pad each side)
#define PLANE (HH * WW)       // 25600
#define NQUADS (CCHUNK * NROWS * (WW / 4))   // 3200 float4 per chunk
#define NSLOT 4               // ceil(3200 / 960); tids >= 320 get 3
#define NACC (RANGE * PXT)    // 36 accumulators per thread

// Second launch_bounds arg MUST stay 1: any min-waves hint makes LLVM cap
// VGPRs and spill acc to scratch (rounds 1-3: 0.8-2.1 GB scratch traffic).
__global__ __launch_bounds__(NTHREADS, 1)
void cost_volume_kernel(const float* __restrict__ f1,
                        const float* __restrict__ f2,
                        float* __restrict__ out) {
    __shared__ __align__(16) float s2[CCHUNK][NROWS][ROWF];   // 53.8 KB

    const int tile_y = blockIdx.x;              // 0..19
    const int bz     = blockIdx.y;              // 0..23
    const int b = bz / NG;
    const int g = bz - b * NG;                  // di group
    const int h0 = tile_y * TH;
    const int tid = threadIdx.x;
    // lane order tx -> r -> ty: duplicate f1 addresses (same tx,ty; diff r)
    // land in the same wave and coalesce to one fetch.
    const int tx = tid % NTX;                   // 0..39
    const int r  = (tid / NTX) % DR;            // 0..2  (this thread's di row)
    const int ty = tid / (NTX * DR);            // 0..7
    const int w = tx * PXT;                     // multiple of 4
    const int h = h0 + ty;
    const int row_start = h0 + DR * g - PAD;    // image row of LDS row 0

    // ---- zero LDS once: pad columns + OOB rows stay zero forever ----
    {
        float* p = &s2[0][0][0];
        for (int i = tid; i < CCHUNK * NROWS * ROWF; i += NTHREADS) p[i] = 0.f;
    }

    // ---- precompute staging slots (channel-invariant) ----
    // slot s -> (cc, row, quad): covers f2[c0+cc][row_start+row][quad*4 .. +3]
    int glb_off[NSLOT];
    int lds_off[NSLOT];
    unsigned vmask = 0;
    {
#pragma unroll
        for (int k = 0; k < NSLOT; k++) {
            const int s = tid + k * NTHREADS;
            const int quad = s % (WW / 4);
            const int t = s / (WW / 4);
            const int row = t % NROWS;
            const int cc = t / NROWS;
            const int gh = row_start + row;
            glb_off[k] = cc * PLANE + gh * WW + quad * 4;
            lds_off[k] = (cc * NROWS + row) * ROWF + PAD + quad * 4;
            if (s < NQUADS && (unsigned)gh < HH) vmask |= (1u << k);
        }
    }

    float acc[NACC];
#pragma unroll
    for (int i = 0; i < NACC; i++) acc[i] = 0.f;

    const float* f1p = f1 + (size_t)b * CC_ALL * PLANE + (size_t)h * WW + w;
    const float* f2b = f2 + (size_t)b * CC_ALL * PLANE;
    float* s2f = &s2[0][0][0];

    __syncthreads();   // zero-init visible before first staging writes

    for (int c0 = 0; c0 < CC_ALL; c0 += CCHUNK) {
        // ---- stage: up to 4 aligned float4 global->LDS per thread ----
#pragma unroll
        for (int k = 0; k < NSLOT; k++) {
            if (vmask & (1u << k)) {
                const float4 v = *(const float4*)(f2b + (size_t)c0 * PLANE + glb_off[k]);
                *(float4*)(s2f + lds_off[k]) = v;
            }
        }
        __syncthreads();

        // ---- compute: one (di row, 4 px) per thread, 9 horizontal disps ----
#pragma unroll
        for (int cc = 0; cc < CCHUNK; cc++) {
            const float4 a = *(const float4*)(f1p + (size_t)(c0 + cc) * PLANE);
            const float av[PXT] = {a.x, a.y, a.z, a.w};
            // LDS cols 4tx .. 4tx+11  <->  image w-4 .. w+7 : 3 aligned b128
            const float* rp = &s2[cc][ty + r][w];
            float win[12];
            *(float4*)&win[0] = *(const float4*)(rp);
            *(float4*)&win[4] = *(const float4*)(rp + 4);
            *(float4*)&win[8] = *(const float4*)(rp + 8);
#pragma unroll
            for (int dj = 0; dj < RANGE; dj++) {
#pragma unroll
                for (int p = 0; p < PXT; p++) {
                    acc[dj * PXT + p] += av[p] * win[dj + p];
                }
            }
        }
        __syncthreads();
    }

    // ---- epilogue: mean and store (skip center lin==40) ----
    float* ob = out + (size_t)b * ND * PLANE + (size_t)h * WW + w;
#pragma unroll
    for (int dj = 0; dj < RANGE; dj++) {
        const int lin = (DR * g + r) * RANGE + dj;
        if (lin == 40) continue;                // per-lane skip, one block set
        const int d = lin - (lin > 40 ? 1 : 0);
        float4 o;
        o.x = acc[dj * PXT + 0] * (1.f / 128.f);
        o.y = acc[dj * PXT + 1] * (1.f / 128.f);
        o.z = acc[dj * PXT + 2] * (1.f / 128.f);
        o.w = acc[dj * PXT + 3] * (1.f / 128.f);
        *(float4*)(ob + (size_t)d * PLANE) = o;
    }
}

extern "C" void kernel_launch(void* const* d_in, const int* in_sizes, int n_in,
                              void* d_out, int out_size, void* d_ws, size_t ws_size,
                              hipStream_t stream) {
    const float* feat1 = (const float*)d_in[0];
    const float* feat2 = (const float*)d_in[1];
    float* out = (float*)d_out;

    dim3 grid(HH / TH, BB * NG);   // 20 x 24 = 480 blocks of 15 waves
    dim3 block(NTHREADS);
    cost_volume_kernel<<<grid, block, 0, stream>>>(feat1, feat2, out);
}